// Round 7
// baseline (1122.735 us; speedup 1.0000x reference)
//
#include <hip/hip_runtime.h>
#include <hip/hip_cooperative_groups.h>
#include <cstdint>
#include <cstddef>

namespace cg = cooperative_groups;

#define D 128
#define P_DROP 0.1f
#define INV_KEEP (1.0f / 0.9f)
#define BN_EPS 1e-5f

typedef __attribute__((ext_vector_type(8))) short bf16x8;
typedef __attribute__((ext_vector_type(4))) float f32x4;

__device__ __forceinline__ unsigned f2bf(float f) {
    unsigned u = __float_as_uint(f);
    return (u + 0x7fffu + ((u >> 16) & 1u)) >> 16;
}
__device__ __forceinline__ float bf_lo(unsigned v) { return __uint_as_float(v << 16); }
__device__ __forceinline__ float bf_hi(unsigned v) { return __uint_as_float(v & 0xffff0000u); }
__device__ __forceinline__ float rl_f(float v, int l) {
    return __int_as_float(__builtin_amdgcn_readlane(__float_as_int(v), l));
}

struct KParams {
    const float* bias; const float* gamma; const float* beta; const float* du;
    const int* esrc; const int* edst;
    float* out;
    const unsigned short* xwb;      // bf16 (x@W), UNSCALED
    int* hist; int* cursor; int* tmp; int* blocksum; int* blockoff;
    int* ssrc; int* sdst;           // dst-sorted edges incl. self loops, +64 pad
    float* dinv; float* bnacc;
    int N, E, NBLK, NTASK, total4;
};

// ================= phase device functions (shared by coop + fallback) =========

__device__ __forceinline__ void dev_zero(const KParams& p, int gt, int gstride) {
    float4 z = make_float4(0.f, 0.f, 0.f, 0.f);
    float4* y4 = (float4*)p.out;
    for (int i = gt; i < p.total4; i += gstride) y4[i] = z;
    for (int i = gt; i < p.N; i += gstride) p.hist[i] = 0;
    int EN = p.E + p.N;
    if (gt < 256) p.bnacc[gt] = 0.f;
    if (gt < 64) { p.ssrc[EN + gt] = 0; p.sdst[EN + gt] = -1; }
}

__device__ __forceinline__ void dev_hist(const KParams& p, int gt, int gstride) {
    for (int i = gt; i < p.E; i += gstride) atomicAdd(&p.hist[p.edst[i]], 1);
}

__device__ __forceinline__ void dev_scanA(const KParams& p, int* sd,
                                          int bid, int gsz, int tid) {
    for (int c = bid; c < p.NBLK; c += gsz) {
        int i = c * 256 + tid;
        sd[tid] = (i < p.N) ? p.hist[i] + 1 : 0;   // +1: self loop
        __syncthreads();
        for (int o = 1; o < 256; o <<= 1) {
            int t = (tid >= o) ? sd[tid - o] : 0;
            __syncthreads();
            sd[tid] += t;
            __syncthreads();
        }
        p.tmp[i] = sd[tid];
        if (tid == 255) p.blocksum[c] = sd[255];
        __syncthreads();
    }
}

__device__ __forceinline__ void dev_scanB(const KParams& p, int* sd, int tid) {
    int v = (tid < p.NBLK) ? p.blocksum[tid] : 0;
    sd[tid] = v;
    __syncthreads();
    for (int o = 1; o < 256; o <<= 1) {
        int t = (tid >= o) ? sd[tid - o] : 0;
        __syncthreads();
        sd[tid] += t;
        __syncthreads();
    }
    if (tid < p.NBLK) p.blockoff[tid] = sd[tid] - v;
}

__device__ __forceinline__ void dev_scanC(const KParams& p, int bid, int gsz, int tid) {
    for (int c = bid; c < p.NBLK; c += gsz) {
        int i = c * 256 + tid;
        if (i < p.N) {
            int deg1 = p.hist[i] + 1;
            p.cursor[i] = p.tmp[i] + p.blockoff[c] - deg1;
            p.dinv[i] = rsqrtf((float)deg1);
        }
    }
}

__device__ __forceinline__ void dev_place(const KParams& p, int gt, int gstride) {
    for (int i = gt; i < p.E; i += gstride) {
        int d = p.edst[i];
        int q = atomicAdd(&p.cursor[d], 1);
        p.ssrc[q] = p.esrc[i];
        p.sdst[q] = d;
    }
    for (int n = gt; n < p.N; n += gstride) {     // self loops
        int q = atomicAdd(&p.cursor[n], 1);
        p.ssrc[q] = n;
        p.sdst[q] = n;
    }
}

__device__ __forceinline__ void dev_agg(const KParams& p, int gw0, int totw, int lane) {
    for (int w = gw0; w < p.NTASK; w += totw) {
        int e0 = w * 64;
        int vsrc = p.ssrc[e0 + lane];
        int vdst = p.sdst[e0 + lane];
        int prevd = (w > 0) ? __builtin_amdgcn_readfirstlane(p.sdst[e0 - 1]) : -5;
        int nextd = __builtin_amdgcn_readfirstlane(p.sdst[e0 + 64]);
        float dvv = p.dinv[vdst < 0 ? 0 : vdst];   // dinv[dst] per lane-edge
        float dss = p.dinv[vsrc];                  // dinv[src] per lane-edge
        float a0 = 0.f, a1 = 0.f;
        int cur = __builtin_amdgcn_readlane(vdst, 0);
        bool excl = (prevd != cur);
        unsigned vrow[32];
#pragma unroll
        for (int half = 0; half < 2; ++half) {
            int base = half * 32;
#pragma unroll
            for (int j = 0; j < 32; ++j) {
                int idx = __builtin_amdgcn_readlane(vsrc, base + j);
                vrow[j] = *(const unsigned*)(p.xwb + (size_t)idx * D + lane * 2);
            }
#pragma unroll
            for (int j = 0; j < 32; ++j) {
                int gj = base + j;
                int dj = __builtin_amdgcn_readlane(vdst, gj);
                if (dj != cur) {
                    float dv = rl_f(dvv, gj - 1);
                    float s0 = a0 * dv, s1 = a1 * dv;
                    float* yp = p.out + (size_t)cur * D + lane * 2;
                    if (excl) { *(float2*)yp = make_float2(s0, s1); }
                    else { atomicAdd(yp, s0); atomicAdd(yp + 1, s1); }
                    a0 = 0.f; a1 = 0.f; cur = dj; excl = true;
                }
                float ds = rl_f(dss, gj);
                unsigned v = vrow[j];
                a0 = fmaf(bf_lo(v), ds, a0);
                a1 = fmaf(bf_hi(v), ds, a1);
            }
        }
        if (cur >= 0) {
            float dv = rl_f(dvv, 63);
            float s0 = a0 * dv, s1 = a1 * dv;
            float* yp = p.out + (size_t)cur * D + lane * 2;
            if (excl && (nextd != cur)) { *(float2*)yp = make_float2(s0, s1); }
            else { atomicAdd(yp, s0); atomicAdd(yp + 1, s1); }
        }
    }
}

__device__ __forceinline__ void dev_stats(const KParams& p, float (*red)[8],
                                          int tid, int gt, int gstride) {
    int c4 = gt & 31;
    float4 b4 = ((const float4*)p.bias)[c4];
    float s0 = 0.f, s1 = 0.f, s2 = 0.f, s3 = 0.f;
    float q0 = 0.f, q1 = 0.f, q2 = 0.f, q3 = 0.f;
    for (int i = gt; i < p.total4; i += gstride) {
        float4 z = ((const float4*)p.out)[i];
        z.x = fmaxf(z.x + b4.x, 0.f);
        z.y = fmaxf(z.y + b4.y, 0.f);
        z.z = fmaxf(z.z + b4.z, 0.f);
        z.w = fmaxf(z.w + b4.w, 0.f);
        s0 += z.x; s1 += z.y; s2 += z.z; s3 += z.w;
        q0 += z.x * z.x; q1 += z.y * z.y; q2 += z.z * z.z; q3 += z.w * z.w;
    }
    red[tid][0] = s0; red[tid][1] = s1; red[tid][2] = s2; red[tid][3] = s3;
    red[tid][4] = q0; red[tid][5] = q1; red[tid][6] = q2; red[tid][7] = q3;
    __syncthreads();
    if (tid < 128) {
        int r0 = tid >> 2, sl = tid & 3;
        float acc = 0.f;
#pragma unroll
        for (int m = 0; m < 8; ++m) acc += red[r0 + 32 * m][sl];
        atomicAdd(&p.bnacc[tid], acc);
    } else {
        int t2 = tid - 128;
        int r0 = t2 >> 2, sl = 4 + (t2 & 3);
        float acc = 0.f;
#pragma unroll
        for (int m = 0; m < 8; ++m) acc += red[r0 + 32 * m][sl];
        atomicAdd(&p.bnacc[128 + t2], acc);
    }
}

__device__ __forceinline__ void dev_final(const KParams& p, float* scl, float* shf,
                                          int tid, int gt, int gstride) {
    if (tid < 128) {
        float invN = 1.0f / (float)p.N;
        float mean = p.bnacc[tid] * invN;
        float var = fmaxf(p.bnacc[128 + tid] * invN - mean * mean, 0.f);
        float sc = p.gamma[tid] * rsqrtf(var + BN_EPS);
        scl[tid] = sc;
        shf[tid] = p.beta[tid] - mean * sc;
    }
    __syncthreads();
    int c4 = gt & 31;
    float4 b4 = ((const float4*)p.bias)[c4];
    float sc0 = scl[c4 * 4], sc1 = scl[c4 * 4 + 1], sc2 = scl[c4 * 4 + 2], sc3 = scl[c4 * 4 + 3];
    float sh0 = shf[c4 * 4], sh1 = shf[c4 * 4 + 1], sh2 = shf[c4 * 4 + 2], sh3 = shf[c4 * 4 + 3];
    for (int i = gt; i < p.total4; i += gstride) {
        float4 z = ((const float4*)p.out)[i];
        float4 uu = ((const float4*)p.du)[i];
        z.x = fmaxf(z.x + b4.x, 0.f);
        z.y = fmaxf(z.y + b4.y, 0.f);
        z.z = fmaxf(z.z + b4.z, 0.f);
        z.w = fmaxf(z.w + b4.w, 0.f);
        float4 v;
        v.x = fmaf(z.x, sc0, sh0) * (uu.x > P_DROP ? INV_KEEP : 0.f);
        v.y = fmaf(z.y, sc1, sh1) * (uu.y > P_DROP ? INV_KEEP : 0.f);
        v.z = fmaf(z.z, sc2, sh2) * (uu.z > P_DROP ? INV_KEEP : 0.f);
        v.w = fmaf(z.w, sc3, sh3) * (uu.w > P_DROP ? INV_KEEP : 0.f);
        ((float4*)p.out)[i] = v;
    }
}

// ================= standalone MFMA GEMM (ordinary launch) =====================
__global__ __launch_bounds__(256) void k_gemm(
    const float* __restrict__ x, const float* __restrict__ w,
    unsigned short* __restrict__ xwb, int N) {
    __shared__ unsigned short xs[64][136];
    __shared__ unsigned short wt[128][136];
    int tid = threadIdx.x;
    int row0 = blockIdx.x * 64;
#pragma unroll
    for (int i = 0; i < 32; ++i) {
        int flat = tid + i * 256;
        int n = flat & 127, kp = flat >> 7;
        float a0 = w[(size_t)(2 * kp) * D + n];
        float a1 = w[(size_t)(2 * kp + 1) * D + n];
        *(unsigned*)&wt[n][2 * kp] = f2bf(a0) | (f2bf(a1) << 16);
    }
#pragma unroll
    for (int i = 0; i < 8; ++i) {
        int flat = tid + i * 256;
        int r = flat >> 5, kq = flat & 31;
        int row = row0 + r;
        float4 v = (row < N) ? *(const float4*)&x[(size_t)row * D + kq * 4]
                             : make_float4(0.f, 0.f, 0.f, 0.f);
        uint2 pk;
        pk.x = f2bf(v.x) | (f2bf(v.y) << 16);
        pk.y = f2bf(v.z) | (f2bf(v.w) << 16);
        *(uint2*)&xs[r][kq * 4] = pk;
    }
    __syncthreads();
    int wv = tid >> 6, lane = tid & 63;
    int l15 = lane & 15, quad = lane >> 4;
    int mrow = wv * 16 + l15;
    f32x4 acc[8];
#pragma unroll
    for (int a = 0; a < 8; ++a) acc[a] = (f32x4){0.f, 0.f, 0.f, 0.f};
#pragma unroll
    for (int k0 = 0; k0 < D; k0 += 32) {
        bf16x8 af = *(bf16x8*)&xs[mrow][k0 + quad * 8];
#pragma unroll
        for (int nt = 0; nt < 8; ++nt) {
            bf16x8 bfr = *(bf16x8*)&wt[nt * 16 + l15][k0 + quad * 8];
            acc[nt] = __builtin_amdgcn_mfma_f32_16x16x32_bf16(af, bfr, acc[nt], 0, 0, 0);
        }
    }
#pragma unroll
    for (int reg = 0; reg < 4; ++reg) {
        int node = row0 + wv * 16 + quad * 4 + reg;
        if (node < N) {
#pragma unroll
            for (int nt = 0; nt < 8; ++nt)
                xwb[(size_t)node * D + nt * 16 + l15] = (unsigned short)f2bf(acc[nt][reg]);
        }
    }
}

// ================= cooperative fused kernel ==================================
__global__ __launch_bounds__(256, 6) void k_coop(KParams p) {
    cg::grid_group grid = cg::this_grid();
    __shared__ __align__(16) unsigned char SH[8192];
    const int tid = threadIdx.x;
    const int bid = blockIdx.x;
    const int gsz = gridDim.x;
    const int gt = bid * 256 + tid;
    const int gstride = gsz * 256;

    dev_zero(p, gt, gstride);
    grid.sync();
    dev_hist(p, gt, gstride);
    grid.sync();
    dev_scanA(p, (int*)SH, bid, gsz, tid);
    grid.sync();
    if (bid == 0) dev_scanB(p, (int*)SH, tid);
    grid.sync();
    dev_scanC(p, bid, gsz, tid);
    grid.sync();
    dev_place(p, gt, gstride);
    grid.sync();
    dev_agg(p, bid * 4 + (tid >> 6), gsz * 4, tid & 63);
    grid.sync();
    dev_stats(p, (float (*)[8])SH, tid, gt, gstride);
    grid.sync();
    dev_final(p, (float*)SH, (float*)(SH + 512), tid, gt, gstride);
}

// ================= fallback ordinary wrappers ================================
__global__ void k_w_zero(KParams p) {
    dev_zero(p, blockIdx.x * 256 + threadIdx.x, gridDim.x * 256);
}
__global__ void k_w_hist(KParams p) {
    dev_hist(p, blockIdx.x * 256 + threadIdx.x, gridDim.x * 256);
}
__global__ void k_w_scanA(KParams p) {
    __shared__ int sd[256];
    dev_scanA(p, sd, blockIdx.x, gridDim.x, threadIdx.x);
}
__global__ void k_w_scanB(KParams p) {
    __shared__ int sd[256];
    if (blockIdx.x == 0) dev_scanB(p, sd, threadIdx.x);
}
__global__ void k_w_scanC(KParams p) {
    dev_scanC(p, blockIdx.x, gridDim.x, threadIdx.x);
}
__global__ void k_w_place(KParams p) {
    dev_place(p, blockIdx.x * 256 + threadIdx.x, gridDim.x * 256);
}
__global__ void k_w_agg(KParams p) {
    dev_agg(p, blockIdx.x * 4 + (threadIdx.x >> 6), gridDim.x * 4, threadIdx.x & 63);
}
__global__ void k_w_stats(KParams p) {
    __shared__ float red[256][8];
    dev_stats(p, red, threadIdx.x, blockIdx.x * 256 + threadIdx.x, gridDim.x * 256);
}
__global__ void k_w_final(KParams p) {
    __shared__ float scl[128];
    __shared__ float shf[128];
    dev_final(p, scl, shf, threadIdx.x, blockIdx.x * 256 + threadIdx.x, gridDim.x * 256);
}

extern "C" void kernel_launch(void* const* d_in, const int* in_sizes, int n_in,
                              void* d_out, int out_size, void* d_ws, size_t ws_size,
                              hipStream_t stream) {
    const int N = in_sizes[0] / D;      // 50000
    const int E = in_sizes[6] / 2;      // 600000
    const int EN = E + N;
    const int NBLK = (N + 255) / 256;   // 196

    char* pws = (char*)d_ws;
    auto alloc = [&](size_t bytes) {
        char* q = pws;
        pws += (bytes + 255) & ~(size_t)255;
        return q;
    };
    unsigned short* xwb = (unsigned short*)alloc((size_t)N * D * sizeof(unsigned short));
    int*   hist     = (int*)alloc((size_t)N * sizeof(int));
    int*   cursor   = (int*)alloc((size_t)N * sizeof(int));
    int*   tmp      = (int*)alloc((size_t)NBLK * 256 * sizeof(int));
    int*   blocksum = (int*)alloc((size_t)NBLK * sizeof(int));
    int*   blockoff = (int*)alloc((size_t)NBLK * sizeof(int));
    int*   ssrc     = (int*)alloc((size_t)(EN + 64) * sizeof(int));
    int*   sdst     = (int*)alloc((size_t)(EN + 64) * sizeof(int));
    float* dinv     = (float*)alloc((size_t)N * sizeof(float));
    float* bnacc    = (float*)alloc(256 * sizeof(float));

    KParams prm;
    prm.bias   = (const float*)d_in[2];
    prm.gamma  = (const float*)d_in[3];
    prm.beta   = (const float*)d_in[4];
    prm.du     = (const float*)d_in[5];
    prm.esrc   = (const int*)d_in[6];
    prm.edst   = (const int*)d_in[6] + E;
    prm.out    = (float*)d_out;
    prm.xwb    = xwb;
    prm.hist   = hist;   prm.cursor = cursor;
    prm.tmp    = tmp;    prm.blocksum = blocksum; prm.blockoff = blockoff;
    prm.ssrc   = ssrc;   prm.sdst = sdst;
    prm.dinv   = dinv;   prm.bnacc = bnacc;
    prm.N = N; prm.E = E; prm.NBLK = NBLK;
    prm.NTASK = (EN + 63) / 64;
    prm.total4 = N * (D / 4);

    // GEMM first (independent of graph structure)
    hipLaunchKernelGGL(k_gemm, dim3((N + 63) / 64), dim3(256), 0, stream,
                       (const float*)d_in[0], (const float*)d_in[1], xwb, N);

    // Cooperative fused pipeline, grid clamped to queried occupancy
    int nb = 0;
    hipError_t qerr = hipOccupancyMaxActiveBlocksPerMultiprocessor(
        &nb, (const void*)k_coop, 256, 0);
    if (qerr != hipSuccess || nb < 1) nb = 1;
    if (nb > 8) nb = 8;
    int grid = nb * 256;                 // 256 CUs on MI355X

    void* args[] = { &prm };
    hipError_t lerr = hipLaunchCooperativeKernel((void*)k_coop, dim3(grid), dim3(256),
                                                 args, 0u, stream);
    if (lerr != hipSuccess) {
        // fallback: ordinary multi-kernel pipeline (same device code)
        hipLaunchKernelGGL(k_w_zero, dim3(1024), dim3(256), 0, stream, prm);
        hipLaunchKernelGGL(k_w_hist, dim3((E + 255) / 256), dim3(256), 0, stream, prm);
        hipLaunchKernelGGL(k_w_scanA, dim3(NBLK), dim3(256), 0, stream, prm);
        hipLaunchKernelGGL(k_w_scanB, dim3(1), dim3(256), 0, stream, prm);
        hipLaunchKernelGGL(k_w_scanC, dim3(NBLK), dim3(256), 0, stream, prm);
        hipLaunchKernelGGL(k_w_place, dim3(1024), dim3(256), 0, stream, prm);
        hipLaunchKernelGGL(k_w_agg, dim3((prm.NTASK + 3) / 4), dim3(256), 0, stream, prm);
        hipLaunchKernelGGL(k_w_stats, dim3(1024), dim3(256), 0, stream, prm);
        hipLaunchKernelGGL(k_w_final, dim3(1024), dim3(256), 0, stream, prm);
    }
}

// Round 8
// 305.435 us; speedup vs baseline: 3.6759x; 3.6759x over previous
//
#include <hip/hip_runtime.h>
#include <cstdint>
#include <cstddef>

#define D 128
#define P_DROP 0.1f
#define INV_KEEP (1.0f / 0.9f)
#define BN_EPS 1e-5f

typedef __attribute__((ext_vector_type(8))) short bf16x8;
typedef __attribute__((ext_vector_type(4))) float f32x4;

__device__ __forceinline__ unsigned f2bf(float f) {
    unsigned u = __float_as_uint(f);
    return (u + 0x7fffu + ((u >> 16) & 1u)) >> 16;
}
__device__ __forceinline__ float bf_lo(unsigned v) { return __uint_as_float(v << 16); }
__device__ __forceinline__ float bf_hi(unsigned v) { return __uint_as_float(v & 0xffff0000u); }
__device__ __forceinline__ float rl_f(float v, int l) {
    return __int_as_float(__builtin_amdgcn_readlane(__float_as_int(v), l));
}

// ---- K1: in-degree histogram + y zeroing (independent work fused) ----
__global__ __launch_bounds__(256) void k_hist(
    const int* __restrict__ edst, int* __restrict__ hist, int E,
    float4* __restrict__ y4, int total4) {
    int gt = blockIdx.x * 256 + threadIdx.x;
    int stride = gridDim.x * 256;
    float4 z = make_float4(0.f, 0.f, 0.f, 0.f);
    for (int i = gt; i < total4; i += stride) y4[i] = z;
    for (int i = gt; i < E; i += stride) atomicAdd(&hist[edst[i]], 1);
}

// ---- K2: single-block scan: cursor = exclusive prefix of (deg+1); dinv ----
__global__ __launch_bounds__(1024) void k_scan(
    const int* __restrict__ hist, int* __restrict__ cursor,
    float* __restrict__ dinv, int N) {
    __shared__ int wsum[16];
    __shared__ int carry;
    int tid = threadIdx.x;
    int lane = tid & 63, wv = tid >> 6;
    if (tid == 0) carry = 0;
    __syncthreads();
    const int NC = (N + 1023) >> 10;
    int dnext = (tid < N) ? hist[tid] + 1 : 0;        // +1: self loop
    for (int c = 0; c < NC; ++c) {
        int d = dnext;
        int inext = (c + 1) * 1024 + tid;             // prefetch next chunk
        if (c + 1 < NC) dnext = (inext < N) ? hist[inext] + 1 : 0;
        int base = carry;
        int s = d;                                    // wave inclusive scan
#pragma unroll
        for (int off = 1; off < 64; off <<= 1) {
            int t = __shfl_up(s, off, 64);
            if (lane >= off) s += t;
        }
        if (lane == 63) wsum[wv] = s;
        __syncthreads();
        if (wv == 0 && lane < 16) {                   // scan the 16 wave sums
            int v = wsum[lane];
#pragma unroll
            for (int off = 1; off < 16; off <<= 1) {
                int t = __shfl_up(v, off, 64);
                if (lane >= off) v += t;
            }
            wsum[lane] = v;
        }
        __syncthreads();
        int prefix = base + (wv ? wsum[wv - 1] : 0);
        int i = c * 1024 + tid;
        if (i < N) {
            cursor[i] = prefix + s - d;               // exclusive
            dinv[i] = rsqrtf((float)d);
        }
        if (tid == 0) carry = base + wsum[15];
        __syncthreads();
    }
}

// ---- K3: MFMA GEMM xwb = bf16((x @ W) * dinv[row]) ----
__global__ __launch_bounds__(256) void k_gemm(
    const float* __restrict__ x, const float* __restrict__ w,
    const float* __restrict__ dinv, unsigned short* __restrict__ xwb, int N) {
    __shared__ unsigned short xs[64][136];
    __shared__ unsigned short wt[128][136];
    int tid = threadIdx.x;
    int row0 = blockIdx.x * 64;
#pragma unroll
    for (int i = 0; i < 32; ++i) {
        int flat = tid + i * 256;
        int n = flat & 127, kp = flat >> 7;
        float a0 = w[(size_t)(2 * kp) * D + n];
        float a1 = w[(size_t)(2 * kp + 1) * D + n];
        *(unsigned*)&wt[n][2 * kp] = f2bf(a0) | (f2bf(a1) << 16);
    }
#pragma unroll
    for (int i = 0; i < 8; ++i) {
        int flat = tid + i * 256;
        int r = flat >> 5, kq = flat & 31;
        int row = row0 + r;
        float4 v = (row < N) ? *(const float4*)&x[(size_t)row * D + kq * 4]
                             : make_float4(0.f, 0.f, 0.f, 0.f);
        uint2 pk;
        pk.x = f2bf(v.x) | (f2bf(v.y) << 16);
        pk.y = f2bf(v.z) | (f2bf(v.w) << 16);
        *(uint2*)&xs[r][kq * 4] = pk;
    }
    __syncthreads();
    int wv = tid >> 6, lane = tid & 63;
    int l15 = lane & 15, quad = lane >> 4;
    int mrow = wv * 16 + l15;
    f32x4 acc[8];
#pragma unroll
    for (int a = 0; a < 8; ++a) acc[a] = (f32x4){0.f, 0.f, 0.f, 0.f};
#pragma unroll
    for (int k0 = 0; k0 < D; k0 += 32) {
        bf16x8 af = *(bf16x8*)&xs[mrow][k0 + quad * 8];
#pragma unroll
        for (int nt = 0; nt < 8; ++nt) {
            bf16x8 bfr = *(bf16x8*)&wt[nt * 16 + l15][k0 + quad * 8];
            acc[nt] = __builtin_amdgcn_mfma_f32_16x16x32_bf16(af, bfr, acc[nt], 0, 0, 0);
        }
    }
#pragma unroll
    for (int reg = 0; reg < 4; ++reg) {
        int node = row0 + wv * 16 + quad * 4 + reg;
        if (node < N) {
            float dv = dinv[node];
#pragma unroll
            for (int nt = 0; nt < 8; ++nt) {
                float val = acc[nt][reg] * dv;
                xwb[(size_t)node * D + nt * 16 + l15] = (unsigned short)f2bf(val);
            }
        }
    }
}

// ---- K4: place real + self edges dst-grouped; sentinel pads ----
__global__ __launch_bounds__(256) void k_place(
    const int* __restrict__ esrc, const int* __restrict__ edst,
    int* __restrict__ cursor, int* __restrict__ ssrc, int* __restrict__ sdst,
    int E, int N) {
    int gt = blockIdx.x * 256 + threadIdx.x;
    int stride = gridDim.x * 256;
    if (gt < 64) { ssrc[E + N + gt] = 0; sdst[E + N + gt] = -1; }
    for (int i = gt; i < E; i += stride) {
        int d = edst[i];
        int q = atomicAdd(&cursor[d], 1);
        ssrc[q] = esrc[i];
        sdst[q] = d;
    }
    for (int n = gt; n < N; n += stride) {            // self loops
        int q = atomicAdd(&cursor[n], 1);
        ssrc[q] = n;
        sdst[q] = n;
    }
}

// ---- K5: edge-parallel gather + flush-on-dst-change (R5-exact) ----
__global__ __launch_bounds__(256) void k_agg(
    const unsigned short* __restrict__ xwb, const float* __restrict__ dinv,
    const int* __restrict__ ssrc, const int* __restrict__ sdst,
    float* __restrict__ y, int NTASK) {
    int lane = threadIdx.x & 63;
    int wv = threadIdx.x >> 6;
    int w = blockIdx.x * 4 + wv;
    if (w >= NTASK) return;
    int e0 = w * 64;
    int vsrc = ssrc[e0 + lane];
    int vdst = sdst[e0 + lane];
    int prevd = (w > 0) ? __builtin_amdgcn_readfirstlane(sdst[e0 - 1]) : -5;
    int nextd = __builtin_amdgcn_readfirstlane(sdst[e0 + 64]);
    float dvv = dinv[vdst < 0 ? 0 : vdst];
    float a0 = 0.f, a1 = 0.f;
    int cur = __builtin_amdgcn_readlane(vdst, 0);
    bool excl = (prevd != cur);
    unsigned vrow[32];
#pragma unroll
    for (int half = 0; half < 2; ++half) {
        int base = half * 32;
#pragma unroll
        for (int j = 0; j < 32; ++j) {
            int idx = __builtin_amdgcn_readlane(vsrc, base + j);
            vrow[j] = *(const unsigned*)(xwb + (size_t)idx * D + lane * 2);
        }
#pragma unroll
        for (int j = 0; j < 32; ++j) {
            int gj = base + j;
            int dj = __builtin_amdgcn_readlane(vdst, gj);
            if (dj != cur) {
                float dv = rl_f(dvv, gj - 1);
                float s0 = a0 * dv, s1 = a1 * dv;
                float* yp = y + (size_t)cur * D + lane * 2;
                if (excl) { *(float2*)yp = make_float2(s0, s1); }
                else { atomicAdd(yp, s0); atomicAdd(yp + 1, s1); }
                a0 = 0.f; a1 = 0.f; cur = dj; excl = true;
            }
            unsigned v = vrow[j];
            a0 += bf_lo(v); a1 += bf_hi(v);
        }
    }
    if (cur >= 0) {
        float dv = rl_f(dvv, 63);
        float s0 = a0 * dv, s1 = a1 * dv;
        float* yp = y + (size_t)cur * D + lane * 2;
        if (excl && (nextd != cur)) { *(float2*)yp = make_float2(s0, s1); }
        else { atomicAdd(yp, s0); atomicAdd(yp + 1, s1); }
    }
}

// ---- K6: BN stats (read-only; z = relu(y + bias) recomputed) ----
__global__ __launch_bounds__(256) void k_stats(
    const float* __restrict__ y, const float* __restrict__ bias,
    float* __restrict__ bnacc, int total4) {
    int tid = threadIdx.x;
    int gt = blockIdx.x * 256 + tid;
    int gstride = gridDim.x * 256;
    int c4 = gt & 31;
    float4 b4 = ((const float4*)bias)[c4];
    float s0 = 0.f, s1 = 0.f, s2 = 0.f, s3 = 0.f;
    float q0 = 0.f, q1 = 0.f, q2 = 0.f, q3 = 0.f;
    for (int i = gt; i < total4; i += gstride) {
        float4 z = ((const float4*)y)[i];
        z.x = fmaxf(z.x + b4.x, 0.f);
        z.y = fmaxf(z.y + b4.y, 0.f);
        z.z = fmaxf(z.z + b4.z, 0.f);
        z.w = fmaxf(z.w + b4.w, 0.f);
        s0 += z.x; s1 += z.y; s2 += z.z; s3 += z.w;
        q0 += z.x * z.x; q1 += z.y * z.y; q2 += z.z * z.z; q3 += z.w * z.w;
    }
    __shared__ float red[256][8];
    red[tid][0] = s0; red[tid][1] = s1; red[tid][2] = s2; red[tid][3] = s3;
    red[tid][4] = q0; red[tid][5] = q1; red[tid][6] = q2; red[tid][7] = q3;
    __syncthreads();
    if (tid < 128) {
        int r0 = tid >> 2, sl = tid & 3;
        float acc = 0.f;
#pragma unroll
        for (int m = 0; m < 8; ++m) acc += red[r0 + 32 * m][sl];
        atomicAdd(&bnacc[tid], acc);
    } else {
        int t2 = tid - 128;
        int r0 = t2 >> 2, sl = 4 + (t2 & 3);
        float acc = 0.f;
#pragma unroll
        for (int m = 0; m < 8; ++m) acc += red[r0 + 32 * m][sl];
        atomicAdd(&bnacc[128 + t2], acc);
    }
}

// ---- K7: BN finalize + bias/ReLU/affine/dropout, in place ----
__global__ __launch_bounds__(256) void k_final(
    float* __restrict__ y, const float* __restrict__ du,
    const float* __restrict__ bias, const float* __restrict__ gamma,
    const float* __restrict__ beta, const float* __restrict__ bnacc,
    int N, int total4) {
    __shared__ float scl[128];
    __shared__ float shf[128];
    int tid = threadIdx.x;
    if (tid < 128) {
        float invN = 1.0f / (float)N;
        float mean = bnacc[tid] * invN;
        float var = fmaxf(bnacc[128 + tid] * invN - mean * mean, 0.f);
        float sc = gamma[tid] * rsqrtf(var + BN_EPS);
        scl[tid] = sc;
        shf[tid] = beta[tid] - mean * sc;
    }
    __syncthreads();
    int gt = blockIdx.x * 256 + tid;
    int gstride = gridDim.x * 256;
    int c4 = gt & 31;
    float4 b4 = ((const float4*)bias)[c4];
    float sc0 = scl[c4 * 4], sc1 = scl[c4 * 4 + 1], sc2 = scl[c4 * 4 + 2], sc3 = scl[c4 * 4 + 3];
    float sh0 = shf[c4 * 4], sh1 = shf[c4 * 4 + 1], sh2 = shf[c4 * 4 + 2], sh3 = shf[c4 * 4 + 3];
    for (int i = gt; i < total4; i += gstride) {
        float4 z = ((const float4*)y)[i];
        float4 uu = ((const float4*)du)[i];
        z.x = fmaxf(z.x + b4.x, 0.f);
        z.y = fmaxf(z.y + b4.y, 0.f);
        z.z = fmaxf(z.z + b4.z, 0.f);
        z.w = fmaxf(z.w + b4.w, 0.f);
        float4 v;
        v.x = fmaf(z.x, sc0, sh0) * (uu.x > P_DROP ? INV_KEEP : 0.f);
        v.y = fmaf(z.y, sc1, sh1) * (uu.y > P_DROP ? INV_KEEP : 0.f);
        v.z = fmaf(z.z, sc2, sh2) * (uu.z > P_DROP ? INV_KEEP : 0.f);
        v.w = fmaf(z.w, sc3, sh3) * (uu.w > P_DROP ? INV_KEEP : 0.f);
        ((float4*)y)[i] = v;
    }
}

extern "C" void kernel_launch(void* const* d_in, const int* in_sizes, int n_in,
                              void* d_out, int out_size, void* d_ws, size_t ws_size,
                              hipStream_t stream) {
    const float* x      = (const float*)d_in[0];
    const float* weight = (const float*)d_in[1];
    const float* bias   = (const float*)d_in[2];
    const float* gamma  = (const float*)d_in[3];
    const float* beta   = (const float*)d_in[4];
    const float* du     = (const float*)d_in[5];
    const int*   eidx   = (const int*)d_in[6];
    float* out = (float*)d_out;

    const int N = in_sizes[0] / D;      // 50000
    const int E = in_sizes[6] / 2;      // 600000
    const int EN = E + N;
    const int* esrc = eidx;
    const int* edst = eidx + E;

    char* pws = (char*)d_ws;
    auto alloc = [&](size_t bytes) {
        char* q = pws;
        pws += (bytes + 255) & ~(size_t)255;
        return q;
    };
    unsigned short* xwb = (unsigned short*)alloc((size_t)N * D * sizeof(unsigned short));
    int*   hist   = (int*)alloc((size_t)N * sizeof(int));
    float* bnacc  = (float*)alloc(256 * sizeof(float));   // adjacent to hist: one memset
    int*   cursor = (int*)alloc((size_t)N * sizeof(int));
    int*   ssrc   = (int*)alloc((size_t)(EN + 64) * sizeof(int));
    int*   sdst   = (int*)alloc((size_t)(EN + 64) * sizeof(int));
    float* dinv   = (float*)alloc((size_t)N * sizeof(float));

    const int total4 = N * (D / 4);
    const int NTASK = (EN + 63) / 64;

    // D1: zero hist+bnacc in one memset (contiguous span)
    size_t zspan = (size_t)((char*)(bnacc + 256) - (char*)hist);
    hipMemsetAsync(hist, 0, zspan, stream);
    // D2: histogram + y zeroing
    hipLaunchKernelGGL(k_hist, dim3(1024), dim3(256), 0, stream,
                       edst, hist, E, (float4*)out, total4);
    // D3: single-block scan -> cursor, dinv
    hipLaunchKernelGGL(k_scan, dim3(1), dim3(1024), 0, stream, hist, cursor, dinv, N);
    // D4: MFMA GEMM (scaled by dinv)
    hipLaunchKernelGGL(k_gemm, dim3((N + 63) / 64), dim3(256), 0, stream,
                       x, weight, dinv, xwb, N);
    // D5: placement
    hipLaunchKernelGGL(k_place, dim3(1024), dim3(256), 0, stream,
                       esrc, edst, cursor, ssrc, sdst, E, N);
    // D6: aggregate
    hipLaunchKernelGGL(k_agg, dim3((NTASK + 3) / 4), dim3(256), 0, stream,
                       xwb, dinv, ssrc, sdst, out, NTASK);
    // D7: BN stats
    hipLaunchKernelGGL(k_stats, dim3(1024), dim3(256), 0, stream,
                       out, bias, bnacc, total4);
    // D8: finalize
    hipLaunchKernelGGL(k_final, dim3(1024), dim3(256), 0, stream,
                       out, du, bias, gamma, beta, bnacc, N, total4);
}

// Round 9
// 258.300 us; speedup vs baseline: 4.3466x; 1.1825x over previous
//
#include <hip/hip_runtime.h>
#include <cstdint>
#include <cstddef>

#define D 128
#define P_DROP 0.1f
#define INV_KEEP (1.0f / 0.9f)
#define BN_EPS 1e-5f

typedef __attribute__((ext_vector_type(8))) short bf16x8;
typedef __attribute__((ext_vector_type(4))) float f32x4;

__device__ __forceinline__ unsigned f2bf(float f) {
    unsigned u = __float_as_uint(f);
    return (u + 0x7fffu + ((u >> 16) & 1u)) >> 16;
}
__device__ __forceinline__ float bf_lo(unsigned v) { return __uint_as_float(v << 16); }
__device__ __forceinline__ float bf_hi(unsigned v) { return __uint_as_float(v & 0xffff0000u); }
__device__ __forceinline__ float rl_f(float v, int l) {
    return __int_as_float(__builtin_amdgcn_readlane(__float_as_int(v), l));
}

// ---- K1: in-degree histogram + y zeroing (independent work fused) ----
__global__ __launch_bounds__(256) void k_hist(
    const int* __restrict__ edst, int* __restrict__ hist, int E,
    float4* __restrict__ y4, int total4) {
    int gt = blockIdx.x * 256 + threadIdx.x;
    int stride = gridDim.x * 256;
    float4 z = make_float4(0.f, 0.f, 0.f, 0.f);
    for (int i = gt; i < total4; i += stride) y4[i] = z;
    for (int i = gt; i < E; i += stride) atomicAdd(&hist[edst[i]], 1);
}

// ---- K2a: per-chunk inclusive scan of (deg+1) ----
__global__ __launch_bounds__(256) void k_scanA(
    const int* __restrict__ hist, int* __restrict__ tmp,
    int* __restrict__ blocksum, int N) {
    __shared__ int sd[256];
    int tid = threadIdx.x;
    int i = blockIdx.x * 256 + tid;
    sd[tid] = (i < N) ? hist[i] + 1 : 0;       // +1: self loop
    __syncthreads();
    for (int o = 1; o < 256; o <<= 1) {
        int t = (tid >= o) ? sd[tid - o] : 0;
        __syncthreads();
        sd[tid] += t;
        __syncthreads();
    }
    tmp[i] = sd[tid];
    if (tid == 255) blocksum[blockIdx.x] = sd[255];
}

// ---- K2b: each block redundantly scans block sums, emits cursor + dinv ----
__global__ __launch_bounds__(256) void k_scanC(
    const int* __restrict__ tmp, const int* __restrict__ blocksum,
    const int* __restrict__ hist, int* __restrict__ cursor,
    float* __restrict__ dinv, int N, int NBLK) {
    __shared__ int sd[256];
    int tid = threadIdx.x;
    sd[tid] = (tid < NBLK) ? blocksum[tid] : 0;
    __syncthreads();
    for (int o = 1; o < 256; o <<= 1) {
        int t = (tid >= o) ? sd[tid - o] : 0;
        __syncthreads();
        sd[tid] += t;
        __syncthreads();
    }
    int boff = (blockIdx.x > 0) ? sd[blockIdx.x - 1] : 0;   // exclusive block prefix
    int i = blockIdx.x * 256 + tid;
    if (i < N) {
        int deg1 = hist[i] + 1;
        cursor[i] = tmp[i] + boff - deg1;                   // exclusive element prefix
        dinv[i] = rsqrtf((float)deg1);
    }
}

// ---- K3: MFMA GEMM xwb = bf16((x @ W) * dinv[row]) ----
__global__ __launch_bounds__(256) void k_gemm(
    const float* __restrict__ x, const float* __restrict__ w,
    const float* __restrict__ dinv, unsigned short* __restrict__ xwb, int N) {
    __shared__ unsigned short xs[64][136];
    __shared__ unsigned short wt[128][136];
    int tid = threadIdx.x;
    int row0 = blockIdx.x * 64;
#pragma unroll
    for (int i = 0; i < 32; ++i) {
        int flat = tid + i * 256;
        int n = flat & 127, kp = flat >> 7;
        float a0 = w[(size_t)(2 * kp) * D + n];
        float a1 = w[(size_t)(2 * kp + 1) * D + n];
        *(unsigned*)&wt[n][2 * kp] = f2bf(a0) | (f2bf(a1) << 16);
    }
#pragma unroll
    for (int i = 0; i < 8; ++i) {
        int flat = tid + i * 256;
        int r = flat >> 5, kq = flat & 31;
        int row = row0 + r;
        float4 v = (row < N) ? *(const float4*)&x[(size_t)row * D + kq * 4]
                             : make_float4(0.f, 0.f, 0.f, 0.f);
        uint2 pk;
        pk.x = f2bf(v.x) | (f2bf(v.y) << 16);
        pk.y = f2bf(v.z) | (f2bf(v.w) << 16);
        *(uint2*)&xs[r][kq * 4] = pk;
    }
    __syncthreads();
    int wv = tid >> 6, lane = tid & 63;
    int l15 = lane & 15, quad = lane >> 4;
    int mrow = wv * 16 + l15;
    f32x4 acc[8];
#pragma unroll
    for (int a = 0; a < 8; ++a) acc[a] = (f32x4){0.f, 0.f, 0.f, 0.f};
#pragma unroll
    for (int k0 = 0; k0 < D; k0 += 32) {
        bf16x8 af = *(bf16x8*)&xs[mrow][k0 + quad * 8];
#pragma unroll
        for (int nt = 0; nt < 8; ++nt) {
            bf16x8 bfr = *(bf16x8*)&wt[nt * 16 + l15][k0 + quad * 8];
            acc[nt] = __builtin_amdgcn_mfma_f32_16x16x32_bf16(af, bfr, acc[nt], 0, 0, 0);
        }
    }
#pragma unroll
    for (int reg = 0; reg < 4; ++reg) {
        int node = row0 + wv * 16 + quad * 4 + reg;
        if (node < N) {
            float dv = dinv[node];
#pragma unroll
            for (int nt = 0; nt < 8; ++nt) {
                float val = acc[nt][reg] * dv;
                xwb[(size_t)node * D + nt * 16 + l15] = (unsigned short)f2bf(val);
            }
        }
    }
}

// ---- K4: place real + self edges dst-grouped, packed int2; one thread/edge ----
__global__ __launch_bounds__(256) void k_place(
    const int* __restrict__ esrc, const int* __restrict__ edst,
    int* __restrict__ cursor, int2* __restrict__ epk, int E, int N) {
    int i = blockIdx.x * 256 + threadIdx.x;
    int T = E + N;
    if (i < E) {
        int d = edst[i];
        int q = atomicAdd(&cursor[d], 1);
        epk[q] = make_int2(esrc[i], d);
    } else if (i < T) {
        int n = i - E;                               // self loop
        int q = atomicAdd(&cursor[n], 1);
        epk[q] = make_int2(n, n);
    } else if (i < T + 64) {
        epk[T + (i - T)] = make_int2(0, -1);         // sentinel pad
    }
}

// ---- K5: edge-parallel gather + flush-on-dst-change ----
__global__ __launch_bounds__(256) void k_agg(
    const unsigned short* __restrict__ xwb, const float* __restrict__ dinv,
    const int2* __restrict__ epk, float* __restrict__ y, int NTASK) {
    int lane = threadIdx.x & 63;
    int wv = threadIdx.x >> 6;
    int w = blockIdx.x * 4 + wv;
    if (w >= NTASK) return;
    int e0 = w * 64;
    int2 ed = epk[e0 + lane];
    int vsrc = ed.x, vdst = ed.y;
    int prevd = (w > 0) ? __builtin_amdgcn_readfirstlane(epk[e0 - 1].y) : -5;
    int nextd = __builtin_amdgcn_readfirstlane(epk[e0 + 64].y);
    float dvv = dinv[vdst < 0 ? 0 : vdst];
    float a0 = 0.f, a1 = 0.f;
    int cur = __builtin_amdgcn_readlane(vdst, 0);
    bool excl = (prevd != cur);
    unsigned vrow[32];
#pragma unroll
    for (int half = 0; half < 2; ++half) {
        int base = half * 32;
#pragma unroll
        for (int j = 0; j < 32; ++j) {
            int idx = __builtin_amdgcn_readlane(vsrc, base + j);
            vrow[j] = *(const unsigned*)(xwb + (size_t)idx * D + lane * 2);
        }
#pragma unroll
        for (int j = 0; j < 32; ++j) {
            int gj = base + j;
            int dj = __builtin_amdgcn_readlane(vdst, gj);
            if (dj != cur) {
                float dv = rl_f(dvv, gj - 1);
                float s0 = a0 * dv, s1 = a1 * dv;
                float* yp = y + (size_t)cur * D + lane * 2;
                if (excl) { *(float2*)yp = make_float2(s0, s1); }
                else { atomicAdd(yp, s0); atomicAdd(yp + 1, s1); }
                a0 = 0.f; a1 = 0.f; cur = dj; excl = true;
            }
            unsigned v = vrow[j];
            a0 += bf_lo(v); a1 += bf_hi(v);
        }
    }
    if (cur >= 0) {
        float dv = rl_f(dvv, 63);
        float s0 = a0 * dv, s1 = a1 * dv;
        float* yp = y + (size_t)cur * D + lane * 2;
        if (excl && (nextd != cur)) { *(float2*)yp = make_float2(s0, s1); }
        else { atomicAdd(yp, s0); atomicAdd(yp + 1, s1); }
    }
}

// ---- K6: BN stats (read-only; z = relu(y + bias) recomputed) ----
__global__ __launch_bounds__(256) void k_stats(
    const float* __restrict__ y, const float* __restrict__ bias,
    float* __restrict__ bnacc, int total4) {
    int tid = threadIdx.x;
    int gt = blockIdx.x * 256 + tid;
    int gstride = gridDim.x * 256;
    int c4 = gt & 31;
    float4 b4 = ((const float4*)bias)[c4];
    float s0 = 0.f, s1 = 0.f, s2 = 0.f, s3 = 0.f;
    float q0 = 0.f, q1 = 0.f, q2 = 0.f, q3 = 0.f;
    for (int i = gt; i < total4; i += gstride) {
        float4 z = ((const float4*)y)[i];
        z.x = fmaxf(z.x + b4.x, 0.f);
        z.y = fmaxf(z.y + b4.y, 0.f);
        z.z = fmaxf(z.z + b4.z, 0.f);
        z.w = fmaxf(z.w + b4.w, 0.f);
        s0 += z.x; s1 += z.y; s2 += z.z; s3 += z.w;
        q0 += z.x * z.x; q1 += z.y * z.y; q2 += z.z * z.z; q3 += z.w * z.w;
    }
    __shared__ float red[256][8];
    red[tid][0] = s0; red[tid][1] = s1; red[tid][2] = s2; red[tid][3] = s3;
    red[tid][4] = q0; red[tid][5] = q1; red[tid][6] = q2; red[tid][7] = q3;
    __syncthreads();
    if (tid < 128) {
        int r0 = tid >> 2, sl = tid & 3;
        float acc = 0.f;
#pragma unroll
        for (int m = 0; m < 8; ++m) acc += red[r0 + 32 * m][sl];
        atomicAdd(&bnacc[tid], acc);
    } else {
        int t2 = tid - 128;
        int r0 = t2 >> 2, sl = 4 + (t2 & 3);
        float acc = 0.f;
#pragma unroll
        for (int m = 0; m < 8; ++m) acc += red[r0 + 32 * m][sl];
        atomicAdd(&bnacc[128 + t2], acc);
    }
}

// ---- K7: BN finalize + bias/ReLU/affine/dropout, in place ----
__global__ __launch_bounds__(256) void k_final(
    float* __restrict__ y, const float* __restrict__ du,
    const float* __restrict__ bias, const float* __restrict__ gamma,
    const float* __restrict__ beta, const float* __restrict__ bnacc,
    int N, int total4) {
    __shared__ float scl[128];
    __shared__ float shf[128];
    int tid = threadIdx.x;
    if (tid < 128) {
        float invN = 1.0f / (float)N;
        float mean = bnacc[tid] * invN;
        float var = fmaxf(bnacc[128 + tid] * invN - mean * mean, 0.f);
        float sc = gamma[tid] * rsqrtf(var + BN_EPS);
        scl[tid] = sc;
        shf[tid] = beta[tid] - mean * sc;
    }
    __syncthreads();
    int gt = blockIdx.x * 256 + tid;
    int gstride = gridDim.x * 256;
    int c4 = gt & 31;
    float4 b4 = ((const float4*)bias)[c4];
    float sc0 = scl[c4 * 4], sc1 = scl[c4 * 4 + 1], sc2 = scl[c4 * 4 + 2], sc3 = scl[c4 * 4 + 3];
    float sh0 = shf[c4 * 4], sh1 = shf[c4 * 4 + 1], sh2 = shf[c4 * 4 + 2], sh3 = shf[c4 * 4 + 3];
    for (int i = gt; i < total4; i += gstride) {
        float4 z = ((const float4*)y)[i];
        float4 uu = ((const float4*)du)[i];
        z.x = fmaxf(z.x + b4.x, 0.f);
        z.y = fmaxf(z.y + b4.y, 0.f);
        z.z = fmaxf(z.z + b4.z, 0.f);
        z.w = fmaxf(z.w + b4.w, 0.f);
        float4 v;
        v.x = fmaf(z.x, sc0, sh0) * (uu.x > P_DROP ? INV_KEEP : 0.f);
        v.y = fmaf(z.y, sc1, sh1) * (uu.y > P_DROP ? INV_KEEP : 0.f);
        v.z = fmaf(z.z, sc2, sh2) * (uu.z > P_DROP ? INV_KEEP : 0.f);
        v.w = fmaf(z.w, sc3, sh3) * (uu.w > P_DROP ? INV_KEEP : 0.f);
        ((float4*)y)[i] = v;
    }
}

extern "C" void kernel_launch(void* const* d_in, const int* in_sizes, int n_in,
                              void* d_out, int out_size, void* d_ws, size_t ws_size,
                              hipStream_t stream) {
    const float* x      = (const float*)d_in[0];
    const float* weight = (const float*)d_in[1];
    const float* bias   = (const float*)d_in[2];
    const float* gamma  = (const float*)d_in[3];
    const float* beta   = (const float*)d_in[4];
    const float* du     = (const float*)d_in[5];
    const int*   eidx   = (const int*)d_in[6];
    float* out = (float*)d_out;

    const int N = in_sizes[0] / D;      // 50000
    const int E = in_sizes[6] / 2;      // 600000
    const int EN = E + N;
    const int* esrc = eidx;
    const int* edst = eidx + E;

    char* pws = (char*)d_ws;
    auto alloc = [&](size_t bytes) {
        char* q = pws;
        pws += (bytes + 255) & ~(size_t)255;
        return q;
    };
    unsigned short* xwb = (unsigned short*)alloc((size_t)N * D * sizeof(unsigned short));
    int*   hist   = (int*)alloc((size_t)N * sizeof(int));
    float* bnacc  = (float*)alloc(256 * sizeof(float));   // adjacent to hist: one memset
    int*   cursor = (int*)alloc((size_t)N * sizeof(int));
    const int NBLK = (N + 255) / 256;   // 196
    int*   tmp      = (int*)alloc((size_t)NBLK * 256 * sizeof(int));
    int*   blocksum = (int*)alloc((size_t)NBLK * sizeof(int));
    int2*  epk    = (int2*)alloc((size_t)(EN + 64) * sizeof(int2));
    float* dinv   = (float*)alloc((size_t)N * sizeof(float));

    const int total4 = N * (D / 4);
    const int NTASK = (EN + 63) / 64;

    // D1: zero hist+bnacc in one memset (contiguous span)
    size_t zspan = (size_t)((char*)(bnacc + 256) - (char*)hist);
    hipMemsetAsync(hist, 0, zspan, stream);
    // D2: histogram + y zeroing
    hipLaunchKernelGGL(k_hist, dim3(1024), dim3(256), 0, stream,
                       edst, hist, E, (float4*)out, total4);
    // D3-4: parallel scan -> cursor, dinv
    hipLaunchKernelGGL(k_scanA, dim3(NBLK), dim3(256), 0, stream, hist, tmp, blocksum, N);
    hipLaunchKernelGGL(k_scanC, dim3(NBLK), dim3(256), 0, stream,
                       tmp, blocksum, hist, cursor, dinv, N, NBLK);
    // D5: MFMA GEMM (scaled by dinv)
    hipLaunchKernelGGL(k_gemm, dim3((N + 63) / 64), dim3(256), 0, stream,
                       x, weight, dinv, xwb, N);
    // D6: placement (one thread per edge incl. self loops + sentinels)
    hipLaunchKernelGGL(k_place, dim3((EN + 64 + 255) / 256), dim3(256), 0, stream,
                       esrc, edst, cursor, epk, E, N);
    // D7: aggregate
    hipLaunchKernelGGL(k_agg, dim3((NTASK + 3) / 4), dim3(256), 0, stream,
                       xwb, dinv, epk, out, NTASK);
    // D8: BN stats
    hipLaunchKernelGGL(k_stats, dim3(1024), dim3(256), 0, stream,
                       out, bias, bnacc, total4);
    // D9: finalize
    hipLaunchKernelGGL(k_final, dim3(1024), dim3(256), 0, stream,
                       out, du, bias, gamma, beta, bnacc, N, total4);
}